// Round 14
// baseline (2591.631 us; speedup 1.0000x reference)
//
#include <hip/hip_runtime.h>
#include <cstdint>
#include <cstddef>

#define TOKENS 131072      // B*T = 512*256
#define B_BATCH 512
#define T_SEQ 256
#define C_DIM 512
#define H_HEADS 4
#define HS_DIM 128
#define FF_DIM 2048
#define EPS_RMS 1e-8f
#define SM_SCALE 0.044194173824159216f   // 512^-0.5

typedef short bf16x8 __attribute__((ext_vector_type(8)));
typedef float f32x4 __attribute__((ext_vector_type(4)));
typedef float f32x16 __attribute__((ext_vector_type(16)));
typedef unsigned short ushort_t;

__device__ __forceinline__ ushort_t f2bf(float f) {
    uint32_t u = __builtin_bit_cast(uint32_t, f);
    u += 0x7FFFu + ((u >> 16) & 1u);   // round-to-nearest-even
    return (ushort_t)(u >> 16);
}

__device__ __forceinline__ float bf2f(ushort_t u) {
    return __builtin_bit_cast(float, (uint32_t)u << 16);
}

// tanh-form GELU: |gelu_tanh - gelu_erf| <= ~3e-3 absolute; validated r7/r10/r11
// (absmax unchanged at 0.03125).
__device__ __forceinline__ float gelu_f(float x) {
    float u = 0.7978845608028654f * x + 0.035677408136300125f * (x * x * x);
    float e = __expf(2.0f * u);                 // inf-safe: e=inf -> t=1
    float t = 1.0f - 2.0f / (1.0f + e);         // tanh(u)
    return 0.5f * x * (1.0f + t);
}

// async global->LDS, 16B/lane. Dest must be wave-uniform; HW adds lane*16.
__device__ __forceinline__ void stage8k(ushort_t* lds, const ushort_t* g) {
    __builtin_amdgcn_global_load_lds(
        (const __attribute__((address_space(1))) uint32_t*)g,
        (__attribute__((address_space(3))) uint32_t*)lds,
        16, 0, 0);
}

// ---------------------------------------------------------------------------
// Weight prep: fp32 -> bf16, transposed to N x K row-major
// ---------------------------------------------------------------------------
__global__ void prep_qkv(const float* __restrict__ Wq, const float* __restrict__ Wk,
                         const float* __restrict__ Wv, ushort_t* __restrict__ WqkvT) {
    int idx = blockIdx.x * 256 + threadIdx.x;       // over 1536*512
    if (idx >= 1536 * 512) return;
    int n = idx >> 9;
    int k = idx & 511;
    int h = (n & 511) >> 7;
    int d = n & 127;
    float v;
    size_t s = ((size_t)h * 512 + k) * 128 + d;     // (H,C,HS)
    if (n < 512)       v = Wq[s];
    else if (n < 1024) v = Wk[s];
    else               v = Wv[s];
    WqkvT[idx] = f2bf(v);
}

__global__ void prep_bias(const float* __restrict__ bk, float* __restrict__ bias1536) {
    int n = blockIdx.x * 256 + threadIdx.x;
    if (n >= 1536) return;
    bias1536[n] = (n >= 512 && n < 1024) ? bk[n - 512] : 0.0f;   // bk flat (H,HS)
}

__global__ void prep_proj(const float* __restrict__ Wproj, ushort_t* __restrict__ WprojT) {
    int idx = blockIdx.x * 256 + threadIdx.x;       // over 512*512
    if (idx >= 512 * 512) return;
    int n = idx >> 9, k = idx & 511;
    WprojT[idx] = f2bf(Wproj[(size_t)k * 512 + n]);
}

__global__ void prep_wi(const float* __restrict__ Wi, ushort_t* __restrict__ WiT) {
    int idx = blockIdx.x * 256 + threadIdx.x;       // over 2*2048*512
    if (idx >= 2 * 2048 * 512) return;
    int b = idx >> 20;
    int rem = idx & 1048575;
    int f = rem >> 9, c = rem & 511;                // WiT[b*2048+f][c] = [4096][512]
    WiT[idx] = f2bf(Wi[((size_t)b * 512 + c) * 2048 + f]);
}

// WoT2[c][br*2048+f] = 0.5 * Wo[br][f][c]  -> [512][4096] row-major over K=4096
__global__ void prep_wo(const float* __restrict__ Wo, ushort_t* __restrict__ WoT2) {
    int idx = blockIdx.x * 256 + threadIdx.x;       // over 512*4096
    if (idx >= 512 * 4096) return;
    int c  = idx >> 12;
    int n2 = idx & 4095;
    int br = n2 >> 11;
    int f  = n2 & 2047;
    WoT2[idx] = f2bf(0.5f * Wo[(((size_t)br * 2048 + f) * 512) + c]);
}

// ---------------------------------------------------------------------------
// RMSNorm: one wave per token (512 floats, 8/lane); bf16 out only.
// ---------------------------------------------------------------------------
__global__ __launch_bounds__(256) void rmsnorm_kernel(const float* __restrict__ in,
                                                      const float* __restrict__ wptr,
                                                      ushort_t* __restrict__ outb) {
    const int lane = threadIdx.x & 63;
    const int wave = threadIdx.x >> 6;
    const size_t token = (size_t)blockIdx.x * 4 + wave;
    const float* row = in + token * 512;
    float4 v0 = *(const float4*)(row + lane * 8);
    float4 v1 = *(const float4*)(row + lane * 8 + 4);
    float ss = v0.x*v0.x + v0.y*v0.y + v0.z*v0.z + v0.w*v0.w
             + v1.x*v1.x + v1.y*v1.y + v1.z*v1.z + v1.w*v1.w;
    #pragma unroll
    for (int d = 32; d; d >>= 1) ss += __shfl_xor(ss, d);
    float scale = wptr[0] * rsqrtf(ss * (1.0f / 512.0f) + EPS_RMS);
    float vals[8] = {v0.x, v0.y, v0.z, v0.w, v1.x, v1.y, v1.z, v1.w};
    union { ushort_t us[8]; uint4 u4; } pk;
    #pragma unroll
    for (int i = 0; i < 8; i++) pk.us[i] = f2bf(vals[i] * scale);
    *(uint4*)(outb + token * 512 + lane * 8) = pk.u4;
}

// ---------------------------------------------------------------------------
// GEMM 256x256, BK=64, 8-phase FIFO counted-vmcnt(6), 128KB LDS.
// r14 delta vs r13 (best, 2438us): MFMA shape 16x16x32 -> 32x32x16.
// Rationale: m119 measured 32x32 ceiling 2495 TF vs 16x16's 2176 (+15%), and
// per wave/K-tile the MFMA issue count halves (32 ops of ~8cyc vs 64 of ~5)
// while ds_read count is IDENTICAL (24 = (2mf+1nf)*4ks vs (8mf+4nf)*2ks).
// Fragments (32x32x16_bf16): A/B lane mapping row|col = lane&31,
// k = (lane>>5)*8 + e. D (m74/m101-verified): col = lane&31,
// row = (reg&3) + 8*(reg>>2) + 4*(lane>>5).
// Swizzle: granule g = 2*ks + khalf, slot = g ^ (row&7). Per 16-lane quarter
// khalf is uniform and rows span 16 consecutive -> 2 lanes/slot = free (same
// property as the r6-measured zero-conflict 16x16 pattern).
// Schedule/ledger identical to r13 (single end-of-phase barriers, FIFO
// stages, vmcnt(6) at P4/P8; WAR/RAW ledger unchanged - staging and buffer
// geometry untouched). Quadrant (MH,NH): m-frags {2MH,2MH+1} x n-frag {NH},
// 8 MFMA per quadrant-phase.
// MODE 0: Cb = bf16(acc + bias[c])       MODE 1: Cf = acc + bias[c] + X(f32)
// MODE 2: Cb = bf16(gelu(acc))           MODE 3: Cf = bf2f(Xb) + acc
// ---------------------------------------------------------------------------
template<int MODE>
__global__ __launch_bounds__(512) void gemm256(
    const ushort_t* __restrict__ A, const ushort_t* __restrict__ Bt,
    float* Cf, ushort_t* __restrict__ Cb,
    const float* __restrict__ bias, const float* __restrict__ X,
    const ushort_t* __restrict__ Xb,
    int N, int K)
{
    __shared__ __align__(16) ushort_t S[2][2][256 * 64];   // [buf][0=A,1=B] 128KB
    const int tid  = threadIdx.x;
    const int lane = tid & 63;
    const int wave = tid >> 6;
    const int wm = wave >> 2;          // 0..1
    const int wn = wave & 3;           // 0..3

    // XCD-chunked bijective swizzle (nwg % 8 == 0 for all our grids)
    const int nwg  = (int)gridDim.x;
    const int orig = (int)blockIdx.x;
    const int wgid = (orig & 7) * (nwg >> 3) + (orig >> 3);
    const int gx   = N >> 8;
    const int bm = (wgid / gx) << 8;
    const int bn = (wgid % gx) << 8;

    const int NT = K >> 6;             // K-tiles of 64 (NT >= 8, even, here)

    // pre-swizzled global source column (elements): granule (lane&7)^(lane>>3)
    const int sx = (((lane & 7) ^ (lane >> 3)) << 3);

    auto stA = [&](int dbuf, int part, int ts) {
        int tc = ts < NT ? ts : NT - 1;
        #pragma unroll
        for (int i = 0; i < 2; i++) {
            int rbase = i * 128 + part * 64 + wave * 8;
            stage8k(&S[dbuf][0][rbase * 64],
                    A + (size_t)(bm + rbase + (lane >> 3)) * K + tc * 64 + sx);
        }
    };
    auto stB = [&](int dbuf, int part, int ts) {
        int tc = ts < NT ? ts : NT - 1;
        #pragma unroll
        for (int i = 0; i < 2; i++) {
            int rbase = i * 128 + (wave >> 2) * 64 + part * 32 + (wave & 3) * 8;
            stage8k(&S[dbuf][1][rbase * 64],
                    Bt + (size_t)(bn + rbase + (lane >> 3)) * K + tc * 64 + sx);
        }
    };

    const int r32   = lane & 31;
    const int khalf = lane >> 5;
    const int sw    = r32 & 7;
    // per-k-step swizzled granule offsets (elements)
    int ge[4];
    #pragma unroll
    for (int ks = 0; ks < 4; ks++) ge[ks] = ((2 * ks + khalf) ^ sw) << 3;

    f32x16 acc[4][2] = {};                 // [m-frag 0..3][n-frag 0..1]
    bf16x8 a[2][4], bA[4], bB[4];          // a[mf][ks], b[ks]

#define LDA(BUF, MH) { _Pragma("unroll") for (int mf = 0; mf < 2; mf++) { \
    int R = (wm * 128 + (MH) * 64 + mf * 32 + r32) * 64; \
    _Pragma("unroll") for (int ks = 0; ks < 4; ks++) \
        a[mf][ks] = *(const bf16x8*)&S[BUF][0][R + ge[ks]]; } }
#define LDB(BUF, NH, breg) { \
    int R = (wn * 64 + (NH) * 32 + r32) * 64; \
    _Pragma("unroll") for (int ks = 0; ks < 4; ks++) \
        breg[ks] = *(const bf16x8*)&S[BUF][1][R + ge[ks]]; }
#define MM(MH, NH, breg) { __builtin_amdgcn_s_setprio(1); \
    _Pragma("unroll") for (int ks = 0; ks < 4; ks++) \
    _Pragma("unroll") for (int mf = 0; mf < 2; mf++) \
        acc[(MH)*2+mf][NH] = __builtin_amdgcn_mfma_f32_32x32x16_bf16( \
            a[mf][ks], breg[ks], acc[(MH)*2+mf][NH], 0, 0, 0); \
    __builtin_amdgcn_s_setprio(0); }
#define BAR    __builtin_amdgcn_s_barrier()
#define WAITL  { asm volatile("s_waitcnt lgkmcnt(0)" ::: "memory"); __builtin_amdgcn_sched_barrier(0); }
#define WAITLV { asm volatile("s_waitcnt lgkmcnt(0)\n\ts_waitcnt vmcnt(6)" ::: "memory"); __builtin_amdgcn_sched_barrier(0); }

    // prologue: FIFO half-tiles [A0,B0,B1,A1](0) -> buf0, [A0,B0,B1](1) -> buf1
    // = 14 loads; vmcnt(6) drains all of tile0, keeps tile1's 3 halves in flight.
    stA(0, 0, 0); stB(0, 0, 0); stB(0, 1, 0); stA(0, 1, 0);
    stA(1, 0, 1); stB(1, 0, 1); stB(1, 1, 1);
    asm volatile("s_waitcnt vmcnt(6)" ::: "memory");
    __builtin_amdgcn_sched_barrier(0);
    BAR;

    const int NI = NT >> 1;
    for (int I = 0; I < NI; ++I) {
        const int t = 2 * I;
        // ---- K-tile t (buf0); single end-of-phase barriers (r13) ----
        LDA(0, 0); LDB(0, 0, bA);  stA(1, 1, t + 1);  WAITL;  MM(0, 0, bA); BAR;  // P1
        LDB(0, 1, bB);             stA(0, 0, t + 2);  WAITL;  MM(0, 1, bB); BAR;  // P2
        LDA(0, 1);                 stB(0, 0, t + 2);  WAITL;  MM(1, 1, bB); BAR;  // P3
                                   stB(0, 1, t + 2);  WAITLV; MM(1, 0, bA); BAR;  // P4
        // ---- K-tile t+1 (buf1) ----
        LDA(1, 0); LDB(1, 0, bA);  stA(0, 1, t + 2);  WAITL;  MM(0, 0, bA); BAR;  // P5
        LDB(1, 1, bB);             stA(1, 0, t + 3);  WAITL;  MM(0, 1, bB); BAR;  // P6
        LDA(1, 1);                 stB(1, 0, t + 3);  WAITL;  MM(1, 1, bB); BAR;  // P7
                                   stB(1, 1, t + 3);  WAITLV; MM(1, 0, bA); BAR;  // P8
    }
#undef LDA
#undef LDB
#undef MM
#undef BAR
#undef WAITL
#undef WAITLV

    // epilogue: D layout col = lane&31, row = (reg&3) + 8*(reg>>2) + 4*khalf
    #pragma unroll
    for (int mh = 0; mh < 4; mh++) {
        #pragma unroll
        for (int nh = 0; nh < 2; nh++) {
            #pragma unroll
            for (int reg = 0; reg < 16; reg++) {
                int r = bm + wm * 128 + mh * 32 + (reg & 3) + 8 * (reg >> 2) + 4 * khalf;
                int c = bn + wn * 64 + nh * 32 + r32;
                float v = acc[mh][nh][reg];
                size_t idx = (size_t)r * N + c;
                if (MODE == 0)      { Cb[idx] = f2bf(v + bias[c]); }
                else if (MODE == 1) { Cf[idx] = v + bias[c] + X[idx]; }
                else if (MODE == 2) { Cb[idx] = f2bf(gelu_f(v)); }
                else                { Cf[idx] = bf2f(Xb[idx]) + v; }
            }
        }
    }
}

// ---------------------------------------------------------------------------
// Fused causal attention, flash-style (online softmax). Unchanged.
// ---------------------------------------------------------------------------
__global__ __launch_bounds__(256) void attn_kernel(const ushort_t* __restrict__ QKV,
                                                   ushort_t* __restrict__ Ao) {
    __shared__ __align__(16) ushort_t Ks[32 * 136];
    __shared__ __align__(16) ushort_t VsT[128 * 40];
    __shared__ __align__(16) ushort_t Ps[4][16 * 40];
    const int tid  = threadIdx.x;
    const int lane = tid & 63;
    const int wave = tid >> 6;
    const int qtile = blockIdx.x;                 // 0..3
    const int bh = blockIdx.y;                    // local_b * 4 + h
    const int b = bh >> 2;
    const int h = bh & 3;
    const int qb = qtile * 64;
    const int q0 = qb + wave * 16;
    const size_t baseTok = (size_t)b * T_SEQ;

    bf16x8 qf[4];
    {
        const ushort_t* qrow = QKV + (baseTok + q0 + (lane & 15)) * 1536 + h * 128 + (lane >> 4) * 8;
        #pragma unroll
        for (int dc = 0; dc < 4; dc++)
            qf[dc] = *(const bf16x8*)(qrow + dc * 32);
    }

    float m_run[4], l_run[4];
    f32x4 o[8];
    #pragma unroll
    for (int j = 0; j < 4; j++) { m_run[j] = -INFINITY; l_run[j] = 0.0f; }
    #pragma unroll
    for (int nt = 0; nt < 8; nt++) o[nt] = f32x4{0.f, 0.f, 0.f, 0.f};

    const int nchunks = qtile * 2 + 2;
    for (int kc = 0; kc < nchunks; kc++) {
        const int kbase = kc * 32;
        __syncthreads();
        #pragma unroll
        for (int r = 0; r < 2; r++) {
            int li = r * 256 + tid;
            int row = li >> 4;               // 0..31 key within chunk
            int c8 = (li & 15) * 8;          // 0..120 d
            size_t g = (baseTok + kbase + row) * 1536;
            uint4 vk = *(const uint4*)(QKV + g + 512 + h * 128 + c8);
            *(uint4*)(&Ks[row * 136 + c8]) = vk;
            uint4 vv = *(const uint4*)(QKV + g + 1024 + h * 128 + c8);
            ushort_t* pv = (ushort_t*)&vv;
            #pragma unroll
            for (int jj = 0; jj < 8; jj++)
                VsT[(c8 + jj) * 40 + row] = pv[jj];
        }
        __syncthreads();

        if (q0 + 15 >= kbase) {
            f32x4 s0 = {0.f,0.f,0.f,0.f}, s1 = {0.f,0.f,0.f,0.f};
            #pragma unroll
            for (int dc = 0; dc < 4; dc++) {
                bf16x8 kf0 = *(const bf16x8*)(&Ks[(lane & 15) * 136 + dc * 32 + (lane >> 4) * 8]);
                bf16x8 kf1 = *(const bf16x8*)(&Ks[(16 + (lane & 15)) * 136 + dc * 32 + (lane >> 4) * 8]);
                s0 = __builtin_amdgcn_mfma_f32_16x16x32_bf16(qf[dc], kf0, s0, 0, 0, 0);
                s1 = __builtin_amdgcn_mfma_f32_16x16x32_bf16(qf[dc], kf1, s1, 0, 0, 0);
            }
            const int key0 = kbase + (lane & 15);
            const int key1 = key0 + 16;
            float p0[4], p1[4], alpha[4];
            #pragma unroll
            for (int j = 0; j < 4; j++) {
                int qrow = q0 + (lane >> 4) * 4 + j;
                float sv0 = (key0 <= qrow) ? s0[j] * SM_SCALE : -INFINITY;
                float sv1 = (key1 <= qrow) ? s1[j] * SM_SCALE : -INFINITY;
                float mx = fmaxf(sv0, sv1);
                #pragma unroll
                for (int d = 1; d < 16; d <<= 1) mx = fmaxf(mx, __shfl_xor(mx, d));
                float mnew = fmaxf(m_run[j], mx);
                float aa = expf(m_run[j] - mnew);
                p0[j] = expf(sv0 - mnew);
                p1[j] = expf(sv1 - mnew);
                float rs = p0[j] + p1[j];
                #pragma unroll
                for (int d = 1; d < 16; d <<= 1) rs += __shfl_xor(rs, d);
                l_run[j] = l_run[j] * aa + rs;
                m_run[j] = mnew;
                alpha[j] = aa;
            }
            #pragma unroll
            for (int nt = 0; nt < 8; nt++)
                #pragma unroll
                for (int j = 0; j < 4; j++) o[nt][j] *= alpha[j];
            #pragma unroll
            for (int j = 0; j < 4; j++) {
                int rloc = (lane >> 4) * 4 + j;
                Ps[wave][rloc * 40 + (lane & 15)]      = f2bf(p0[j]);
                Ps[wave][rloc * 40 + 16 + (lane & 15)] = f2bf(p1[j]);
            }
            bf16x8 pa = *(const bf16x8*)(&Ps[wave][(lane & 15) * 40 + (lane >> 4) * 8]);
            #pragma unroll
            for (int nt = 0; nt < 8; nt++) {
                bf16x8 vf = *(const bf16x8*)(&VsT[(nt * 16 + (lane & 15)) * 40 + (lane >> 4) * 8]);
                o[nt] = __builtin_amdgcn_mfma_f32_16x16x32_bf16(pa, vf, o[nt], 0, 0, 0);
            }
        }
    }

    #pragma unroll
    for (int j = 0; j < 4; j++) {
        float inv = 1.0f / l_run[j];
        size_t row = baseTok + q0 + (lane >> 4) * 4 + j;
        #pragma unroll
        for (int nt = 0; nt < 8; nt++)
            Ao[row * 512 + h * 128 + nt * 16 + (lane & 15)] = f2bf(o[nt][j] * inv);
    }
}

// ---------------------------------------------------------------------------
extern "C" void kernel_launch(void* const* d_in, const int* in_sizes, int n_in,
                              void* d_out, int out_size, void* d_ws, size_t ws_size,
                              hipStream_t stream) {
    const float* x     = (const float*)d_in[0];
    const float* Wq    = (const float*)d_in[1];
    const float* Wk    = (const float*)d_in[2];
    const float* bk    = (const float*)d_in[3];
    const float* Wv    = (const float*)d_in[4];
    const float* Wproj = (const float*)d_in[5];
    const float* bproj = (const float*)d_in[6];
    const float* w1    = (const float*)d_in[7];
    const float* w2    = (const float*)d_in[8];
    const float* Wi    = (const float*)d_in[9];
    const float* Wo    = (const float*)d_in[10];
    float* out = (float*)d_out;   // also serves as the f32 residual/z buffer
    (void)in_sizes; (void)n_in; (void)out_size;

    char* ws = (char*)d_ws;
    size_t off = 0;
    auto alloc = [&](size_t bytes) -> void* {
        void* p = ws + off;
        off += (bytes + 255) & ~(size_t)255;
        return p;
    };
    // ---- persistent weights (prepped once per call) ----
    ushort_t* WqkvT    = (ushort_t*)alloc((size_t)1536 * 512 * 2);
    float*    bias1536 = (float*)   alloc((size_t)1536 * 4);
    ushort_t* WprojT   = (ushort_t*)alloc((size_t)512 * 512 * 2);
    ushort_t* WiT      = (ushort_t*)alloc((size_t)4096 * 512 * 2);
    ushort_t* WoT2     = (ushort_t*)alloc((size_t)512 * 4096 * 2);
    const size_t weightBytes = off;

    // ---- choose batch-chunk count so scratch fits ws_size ----
    int nchunks = 1;
    while (nchunks < 64) {
        size_t Mc = (size_t)TOKENS / nchunks;
        size_t need = weightBytes + Mc * 512 * 2 + Mc * 4096 * 2 + 4096;
        if (need <= ws_size) break;
        nchunks *= 2;
    }
    const size_t Mc = (size_t)TOKENS / nchunks;          // tokens per chunk
    const int    nbChunk = B_BATCH / nchunks;            // batches per chunk

    ushort_t* hb  = (ushort_t*)alloc(Mc * 512 * 2);      // h -> attn out -> x2 bf16 (time-shared)
    ushort_t* big = (ushort_t*)alloc(Mc * 4096 * 2);     // qkv (1536 wide) -> hmid (4096 wide)

    // ---- weight prep ----
    prep_qkv <<<(1536 * 512 + 255) / 256, 256, 0, stream>>>(Wq, Wk, Wv, WqkvT);
    prep_bias<<<6, 256, 0, stream>>>(bk, bias1536);
    prep_proj<<<1024, 256, 0, stream>>>(Wproj, WprojT);
    prep_wi  <<<8192, 256, 0, stream>>>(Wi, WiT);
    prep_wo  <<<8192, 256, 0, stream>>>(Wo, WoT2);

    for (int ck = 0; ck < nchunks; ck++) {
        const size_t t0 = (size_t)ck * Mc;
        const float* xC   = x + t0 * 512;
        float*       zC   = out + t0 * 512;
        const int    Mi   = (int)Mc;
        const int    mt   = Mi / 256;                    // 256-row M-tiles

        // h = rmsnorm(x, w1) -> hb (bf16)
        rmsnorm_kernel<<<Mi / 4, 256, 0, stream>>>(xC, w1, hb);
        // QKV = h @ WqkvT^T + bias -> big (bf16, width 1536)
        gemm256<0><<<mt * 6, 512, 0, stream>>>(
            hb, WqkvT, nullptr, big, bias1536, nullptr, nullptr, 1536, 512);
        // attention -> hb (bf16, width 512)
        attn_kernel<<<dim3(T_SEQ / 64, nbChunk * H_HEADS), 256, 0, stream>>>(big, hb);
        // z = x + attn @ Wproj + bproj -> zC (f32, lives in d_out)
        gemm256<1><<<mt * 2, 512, 0, stream>>>(
            hb, WprojT, zC, nullptr, bproj, xC, nullptr, 512, 512);
        // x2 = rmsnorm(z, w2) -> hb (bf16 only; no f32 round-trip)
        rmsnorm_kernel<<<Mi / 4, 256, 0, stream>>>(zC, w2, hb);
        // hmid = gelu(x2 @ WiT^T), both branches as N=4096 -> big
        gemm256<2><<<mt * 16, 512, 0, stream>>>(
            hb, WiT, nullptr, big, nullptr, nullptr, nullptr, 4096, 512);
        // out = x2(bf16 hb) + hmid @ WoT2^T   (0.5 folded into WoT2, K=4096)
        gemm256<3><<<mt * 2, 512, 0, stream>>>(
            big, WoT2, zC, nullptr, nullptr, nullptr, hb, 512, 4096);
    }
}

// Round 15
// 2347.249 us; speedup vs baseline: 1.1041x; 1.1041x over previous
//
#include <hip/hip_runtime.h>
#include <cstdint>
#include <cstddef>

#define TOKENS 131072      // B*T = 512*256
#define B_BATCH 512
#define T_SEQ 256
#define C_DIM 512
#define H_HEADS 4
#define HS_DIM 128
#define FF_DIM 2048
#define EPS_RMS 1e-8f
#define SM_SCALE 0.044194173824159216f   // 512^-0.5

typedef short bf16x8 __attribute__((ext_vector_type(8)));
typedef float f32x4 __attribute__((ext_vector_type(4)));
typedef unsigned short ushort_t;

__device__ __forceinline__ ushort_t f2bf(float f) {
    uint32_t u = __builtin_bit_cast(uint32_t, f);
    u += 0x7FFFu + ((u >> 16) & 1u);   // round-to-nearest-even
    return (ushort_t)(u >> 16);
}

__device__ __forceinline__ float bf2f(ushort_t u) {
    return __builtin_bit_cast(float, (uint32_t)u << 16);
}

// tanh-form GELU: |gelu_tanh - gelu_erf| <= ~3e-3 absolute; validated
// r7/r10/r11/r13 (absmax unchanged at 0.03125).
__device__ __forceinline__ float gelu_f(float x) {
    float u = 0.7978845608028654f * x + 0.035677408136300125f * (x * x * x);
    float e = __expf(2.0f * u);                 // inf-safe: e=inf -> t=1
    float t = 1.0f - 2.0f / (1.0f + e);         // tanh(u)
    return 0.5f * x * (1.0f + t);
}

// async global->LDS, 16B/lane. Dest must be wave-uniform; HW adds lane*16.
__device__ __forceinline__ void stage8k(ushort_t* lds, const ushort_t* g) {
    __builtin_amdgcn_global_load_lds(
        (const __attribute__((address_space(1))) uint32_t*)g,
        (__attribute__((address_space(3))) uint32_t*)lds,
        16, 0, 0);
}

// ---------------------------------------------------------------------------
// Weight prep: fp32 -> bf16, transposed to N x K row-major
// ---------------------------------------------------------------------------
__global__ void prep_qkv(const float* __restrict__ Wq, const float* __restrict__ Wk,
                         const float* __restrict__ Wv, ushort_t* __restrict__ WqkvT) {
    int idx = blockIdx.x * 256 + threadIdx.x;       // over 1536*512
    if (idx >= 1536 * 512) return;
    int n = idx >> 9;
    int k = idx & 511;
    int h = (n & 511) >> 7;
    int d = n & 127;
    float v;
    size_t s = ((size_t)h * 512 + k) * 128 + d;     // (H,C,HS)
    if (n < 512)       v = Wq[s];
    else if (n < 1024) v = Wk[s];
    else               v = Wv[s];
    WqkvT[idx] = f2bf(v);
}

__global__ void prep_bias(const float* __restrict__ bk, float* __restrict__ bias1536) {
    int n = blockIdx.x * 256 + threadIdx.x;
    if (n >= 1536) return;
    bias1536[n] = (n >= 512 && n < 1024) ? bk[n - 512] : 0.0f;   // bk flat (H,HS)
}

__global__ void prep_proj(const float* __restrict__ Wproj, ushort_t* __restrict__ WprojT) {
    int idx = blockIdx.x * 256 + threadIdx.x;       // over 512*512
    if (idx >= 512 * 512) return;
    int n = idx >> 9, k = idx & 511;
    WprojT[idx] = f2bf(Wproj[(size_t)k * 512 + n]);
}

__global__ void prep_wi(const float* __restrict__ Wi, ushort_t* __restrict__ WiT) {
    int idx = blockIdx.x * 256 + threadIdx.x;       // over 2*2048*512
    if (idx >= 2 * 2048 * 512) return;
    int b = idx >> 20;
    int rem = idx & 1048575;
    int f = rem >> 9, c = rem & 511;                // WiT[b*2048+f][c] = [4096][512]
    WiT[idx] = f2bf(Wi[((size_t)b * 512 + c) * 2048 + f]);
}

// WoT2[c][br*2048+f] = 0.5 * Wo[br][f][c]  -> [512][4096] row-major over K=4096
__global__ void prep_wo(const float* __restrict__ Wo, ushort_t* __restrict__ WoT2) {
    int idx = blockIdx.x * 256 + threadIdx.x;       // over 512*4096
    if (idx >= 512 * 4096) return;
    int c  = idx >> 12;
    int n2 = idx & 4095;
    int br = n2 >> 11;
    int f  = n2 & 2047;
    WoT2[idx] = f2bf(0.5f * Wo[(((size_t)br * 2048 + f) * 512) + c]);
}

// ---------------------------------------------------------------------------
// RMSNorm (first norm only): one wave per token, f32 in -> bf16 out.
// ---------------------------------------------------------------------------
__global__ __launch_bounds__(256) void rmsnorm_kernel(const float* __restrict__ in,
                                                      const float* __restrict__ wptr,
                                                      ushort_t* __restrict__ outb) {
    const int lane = threadIdx.x & 63;
    const int wave = threadIdx.x >> 6;
    const size_t token = (size_t)blockIdx.x * 4 + wave;
    const float* row = in + token * 512;
    float4 v0 = *(const float4*)(row + lane * 8);
    float4 v1 = *(const float4*)(row + lane * 8 + 4);
    float ss = v0.x*v0.x + v0.y*v0.y + v0.z*v0.z + v0.w*v0.w
             + v1.x*v1.x + v1.y*v1.y + v1.z*v1.z + v1.w*v1.w;
    #pragma unroll
    for (int d = 32; d; d >>= 1) ss += __shfl_xor(ss, d);
    float scale = wptr[0] * rsqrtf(ss * (1.0f / 512.0f) + EPS_RMS);
    float vals[8] = {v0.x, v0.y, v0.z, v0.w, v1.x, v1.y, v1.z, v1.w};
    union { ushort_t us[8]; uint4 u4; } pk;
    #pragma unroll
    for (int i = 0; i < 8; i++) pk.us[i] = f2bf(vals[i] * scale);
    *(uint4*)(outb + token * 512 + lane * 8) = pk.u4;
}

// ---------------------------------------------------------------------------
// Row-scale kernel (replaces second RMSNorm): s[m] = w2 * rsqrt(mean(zb[m]^2)
// + eps). Reads bf16 z (half the f32 traffic); writes 1 float per row. The
// scale is APPLIED in the FFN GEMM epilogues ((s*z)@W = s*(z@W), linearity).
// ---------------------------------------------------------------------------
__global__ __launch_bounds__(256) void rowscale_kernel(const ushort_t* __restrict__ zb,
                                                       const float* __restrict__ wptr,
                                                       float* __restrict__ s) {
    const int lane = threadIdx.x & 63;
    const int wave = threadIdx.x >> 6;
    const size_t token = (size_t)blockIdx.x * 4 + wave;
    bf16x8 v = *(const bf16x8*)(zb + token * 512 + lane * 8);
    float ss = 0.0f;
    #pragma unroll
    for (int i = 0; i < 8; i++) { float f = bf2f((ushort_t)v[i]); ss += f * f; }
    #pragma unroll
    for (int d = 32; d; d >>= 1) ss += __shfl_xor(ss, d);
    if (lane == 0) s[token] = wptr[0] * rsqrtf(ss * (1.0f / 512.0f) + EPS_RMS);
}

// ---------------------------------------------------------------------------
// GEMM 256x256, BK=64, 8-phase FIFO counted-vmcnt(6), 128KB LDS — the r13
// kernel (best measured: 2438us, 0 conflicts) with epilogue-only changes.
// 16x16x32 MFMA restored (r14's 32x32 regressed: swizzle wrong for its read
// pattern -> 2.5e7 conflicts, MfmaUtil unchanged at 24%).
// Schedule: single end-of-phase barriers (r13), FIFO stages, vmcnt(6) at
// P4/P8; WAR/RAW ledger identical to r13 (see r13's comment block).
// MODE 0: Cb = bf16(acc + bias[c])              (QKV)
// MODE 1: Cb = bf16(acc + bias[c] + X[idx])     (proj + residual -> z bf16)
// MODE 2: Cb = bf16(gelu(sc[r] * acc))          (FFN up; rms-scale folded)
// MODE 3: Cf = sc[r] * bf2f(Xb[idx]) + acc      (FFN down; x2 = s*z residual)
// ---------------------------------------------------------------------------
template<int MODE>
__global__ __launch_bounds__(512) void gemm256(
    const ushort_t* __restrict__ A, const ushort_t* __restrict__ Bt,
    float* Cf, ushort_t* __restrict__ Cb,
    const float* __restrict__ bias, const float* __restrict__ X,
    const ushort_t* __restrict__ Xb, const float* __restrict__ sc,
    int N, int K)
{
    __shared__ __align__(16) ushort_t S[2][2][256 * 64];   // [buf][0=A,1=B] 128KB
    const int tid  = threadIdx.x;
    const int lane = tid & 63;
    const int wave = tid >> 6;
    const int wm = wave >> 2;          // 0..1
    const int wn = wave & 3;           // 0..3

    // XCD-chunked bijective swizzle (nwg % 8 == 0 for all our grids)
    const int nwg  = (int)gridDim.x;
    const int orig = (int)blockIdx.x;
    const int wgid = (orig & 7) * (nwg >> 3) + (orig >> 3);
    const int gx   = N >> 8;
    const int bm = (wgid / gx) << 8;
    const int bn = (wgid % gx) << 8;

    const int NT = K >> 6;             // K-tiles of 64 (NT >= 8, even, here)

    // pre-swizzled global source column (elements): granule (lane&7)^(lane>>3)
    const int sx = (((lane & 7) ^ (lane >> 3)) << 3);

    auto stA = [&](int dbuf, int part, int ts) {
        int tc = ts < NT ? ts : NT - 1;
        #pragma unroll
        for (int i = 0; i < 2; i++) {
            int rbase = i * 128 + part * 64 + wave * 8;
            stage8k(&S[dbuf][0][rbase * 64],
                    A + (size_t)(bm + rbase + (lane >> 3)) * K + tc * 64 + sx);
        }
    };
    auto stB = [&](int dbuf, int part, int ts) {
        int tc = ts < NT ? ts : NT - 1;
        #pragma unroll
        for (int i = 0; i < 2; i++) {
            int rbase = i * 128 + (wave >> 2) * 64 + part * 32 + (wave & 3) * 8;
            stage8k(&S[dbuf][1][rbase * 64],
                    Bt + (size_t)(bn + rbase + (lane >> 3)) * K + tc * 64 + sx);
        }
    };

    const int r16 = lane & 15;
    const int l7  = lane & 7;
    const int q   = lane >> 4;
    const int ge0 = ((q)     ^ l7) << 3;   // k-slice 0 granule elems
    const int ge1 = ((4 + q) ^ l7) << 3;   // k-slice 1

    f32x4 acc[8][4] = {};
    bf16x8 a[4][2], bA[2][2], bB[2][2];

#define LDA(BUF, MH) { _Pragma("unroll") for (int mf = 0; mf < 4; mf++) { \
    int R = wm * 128 + (MH) * 64 + mf * 16 + r16; \
    a[mf][0] = *(const bf16x8*)&S[BUF][0][R * 64 + ge0]; \
    a[mf][1] = *(const bf16x8*)&S[BUF][0][R * 64 + ge1]; } }
#define LDB(BUF, NH, breg) { _Pragma("unroll") for (int nf = 0; nf < 2; nf++) { \
    int R = wn * 64 + (NH) * 32 + nf * 16 + r16; \
    breg[nf][0] = *(const bf16x8*)&S[BUF][1][R * 64 + ge0]; \
    breg[nf][1] = *(const bf16x8*)&S[BUF][1][R * 64 + ge1]; } }
#define MM(MH, NH, breg) { __builtin_amdgcn_s_setprio(1); \
    _Pragma("unroll") for (int mf = 0; mf < 4; mf++) \
    _Pragma("unroll") for (int nf = 0; nf < 2; nf++) { \
        f32x4 t0 = __builtin_amdgcn_mfma_f32_16x16x32_bf16(a[mf][0], breg[nf][0], acc[(MH)*4+mf][(NH)*2+nf], 0, 0, 0); \
        acc[(MH)*4+mf][(NH)*2+nf] = __builtin_amdgcn_mfma_f32_16x16x32_bf16(a[mf][1], breg[nf][1], t0, 0, 0, 0); } \
    __builtin_amdgcn_s_setprio(0); }
#define BAR    __builtin_amdgcn_s_barrier()
#define WAITL  { asm volatile("s_waitcnt lgkmcnt(0)" ::: "memory"); __builtin_amdgcn_sched_barrier(0); }
#define WAITLV { asm volatile("s_waitcnt lgkmcnt(0)\n\ts_waitcnt vmcnt(6)" ::: "memory"); __builtin_amdgcn_sched_barrier(0); }

    // prologue: FIFO half-tiles [A0,B0,B1,A1](0) -> buf0, [A0,B0,B1](1) -> buf1
    stA(0, 0, 0); stB(0, 0, 0); stB(0, 1, 0); stA(0, 1, 0);
    stA(1, 0, 1); stB(1, 0, 1); stB(1, 1, 1);
    asm volatile("s_waitcnt vmcnt(6)" ::: "memory");
    __builtin_amdgcn_sched_barrier(0);
    BAR;

    const int NI = NT >> 1;
    for (int I = 0; I < NI; ++I) {
        const int t = 2 * I;
        // ---- K-tile t (buf0); single end-of-phase barriers ----
        LDA(0, 0); LDB(0, 0, bA);  stA(1, 1, t + 1);  WAITL;  MM(0, 0, bA); BAR;  // P1
        LDB(0, 1, bB);             stA(0, 0, t + 2);  WAITL;  MM(0, 1, bB); BAR;  // P2
        LDA(0, 1);                 stB(0, 0, t + 2);  WAITL;  MM(1, 1, bB); BAR;  // P3
                                   stB(0, 1, t + 2);  WAITLV; MM(1, 0, bA); BAR;  // P4
        // ---- K-tile t+1 (buf1) ----
        LDA(1, 0); LDB(1, 0, bA);  stA(0, 1, t + 2);  WAITL;  MM(0, 0, bA); BAR;  // P5
        LDB(1, 1, bB);             stA(1, 0, t + 3);  WAITL;  MM(0, 1, bB); BAR;  // P6
        LDA(1, 1);                 stB(1, 0, t + 3);  WAITL;  MM(1, 1, bB); BAR;  // P7
                                   stB(1, 1, t + 3);  WAITLV; MM(1, 0, bA); BAR;  // P8
    }
#undef LDA
#undef LDB
#undef MM
#undef BAR
#undef WAITL
#undef WAITLV

    #pragma unroll
    for (int mf = 0; mf < 8; mf++) {
        #pragma unroll
        for (int nf = 0; nf < 4; nf++) {
            #pragma unroll
            for (int j = 0; j < 4; j++) {
                int r = bm + wm * 128 + mf * 16 + (lane >> 4) * 4 + j;
                int c = bn + wn * 64 + nf * 16 + r16;
                float v = acc[mf][nf][j];
                size_t idx = (size_t)r * N + c;
                if (MODE == 0)      { Cb[idx] = f2bf(v + bias[c]); }
                else if (MODE == 1) { Cb[idx] = f2bf(v + bias[c] + X[idx]); }
                else if (MODE == 2) { Cb[idx] = f2bf(gelu_f(sc[r] * v)); }
                else                { Cf[idx] = sc[r] * bf2f(Xb[idx]) + v; }
            }
        }
    }
}

// ---------------------------------------------------------------------------
// Fused causal attention, flash-style (online softmax). Unchanged.
// ---------------------------------------------------------------------------
__global__ __launch_bounds__(256) void attn_kernel(const ushort_t* __restrict__ QKV,
                                                   ushort_t* __restrict__ Ao) {
    __shared__ __align__(16) ushort_t Ks[32 * 136];
    __shared__ __align__(16) ushort_t VsT[128 * 40];
    __shared__ __align__(16) ushort_t Ps[4][16 * 40];
    const int tid  = threadIdx.x;
    const int lane = tid & 63;
    const int wave = tid >> 6;
    const int qtile = blockIdx.x;                 // 0..3
    const int bh = blockIdx.y;                    // local_b * 4 + h
    const int b = bh >> 2;
    const int h = bh & 3;
    const int qb = qtile * 64;
    const int q0 = qb + wave * 16;
    const size_t baseTok = (size_t)b * T_SEQ;

    bf16x8 qf[4];
    {
        const ushort_t* qrow = QKV + (baseTok + q0 + (lane & 15)) * 1536 + h * 128 + (lane >> 4) * 8;
        #pragma unroll
        for (int dc = 0; dc < 4; dc++)
            qf[dc] = *(const bf16x8*)(qrow + dc * 32);
    }

    float m_run[4], l_run[4];
    f32x4 o[8];
    #pragma unroll
    for (int j = 0; j < 4; j++) { m_run[j] = -INFINITY; l_run[j] = 0.0f; }
    #pragma unroll
    for (int nt = 0; nt < 8; nt++) o[nt] = f32x4{0.f, 0.f, 0.f, 0.f};

    const int nchunks = qtile * 2 + 2;
    for (int kc = 0; kc < nchunks; kc++) {
        const int kbase = kc * 32;
        __syncthreads();
        #pragma unroll
        for (int r = 0; r < 2; r++) {
            int li = r * 256 + tid;
            int row = li >> 4;               // 0..31 key within chunk
            int c8 = (li & 15) * 8;          // 0..120 d
            size_t g = (baseTok + kbase + row) * 1536;
            uint4 vk = *(const uint4*)(QKV + g + 512 + h * 128 + c8);
            *(uint4*)(&Ks[row * 136 + c8]) = vk;
            uint4 vv = *(const uint4*)(QKV + g + 1024 + h * 128 + c8);
            ushort_t* pv = (ushort_t*)&vv;
            #pragma unroll
            for (int jj = 0; jj < 8; jj++)
                VsT[(c8 + jj) * 40 + row] = pv[jj];
        }
        __syncthreads();

        if (q0 + 15 >= kbase) {
            f32x4 s0 = {0.f,0.f,0.f,0.f}, s1 = {0.f,0.f,0.f,0.f};
            #pragma unroll
            for (int dc = 0; dc < 4; dc++) {
                bf16x8 kf0 = *(const bf16x8*)(&Ks[(lane & 15) * 136 + dc * 32 + (lane >> 4) * 8]);
                bf16x8 kf1 = *(const bf16x8*)(&Ks[(16 + (lane & 15)) * 136 + dc * 32 + (lane >> 4) * 8]);
                s0 = __builtin_amdgcn_mfma_f32_16x16x32_bf16(qf[dc], kf0, s0, 0, 0, 0);
                s1 = __builtin_amdgcn_mfma_f32_16x16x32_bf16(qf[dc], kf1, s1, 0, 0, 0);
            }
            const int key0 = kbase + (lane & 15);
            const int key1 = key0 + 16;
            float p0[4], p1[4], alpha[4];
            #pragma unroll
            for (int j = 0; j < 4; j++) {
                int qrow = q0 + (lane >> 4) * 4 + j;
                float sv0 = (key0 <= qrow) ? s0[j] * SM_SCALE : -INFINITY;
                float sv1 = (key1 <= qrow) ? s1[j] * SM_SCALE : -INFINITY;
                float mx = fmaxf(sv0, sv1);
                #pragma unroll
                for (int d = 1; d < 16; d <<= 1) mx = fmaxf(mx, __shfl_xor(mx, d));
                float mnew = fmaxf(m_run[j], mx);
                float aa = expf(m_run[j] - mnew);
                p0[j] = expf(sv0 - mnew);
                p1[j] = expf(sv1 - mnew);
                float rs = p0[j] + p1[j];
                #pragma unroll
                for (int d = 1; d < 16; d <<= 1) rs += __shfl_xor(rs, d);
                l_run[j] = l_run[j] * aa + rs;
                m_run[j] = mnew;
                alpha[j] = aa;
            }
            #pragma unroll
            for (int nt = 0; nt < 8; nt++)
                #pragma unroll
                for (int j = 0; j < 4; j++) o[nt][j] *= alpha[j];
            #pragma unroll
            for (int j = 0; j < 4; j++) {
                int rloc = (lane >> 4) * 4 + j;
                Ps[wave][rloc * 40 + (lane & 15)]      = f2bf(p0[j]);
                Ps[wave][rloc * 40 + 16 + (lane & 15)] = f2bf(p1[j]);
            }
            bf16x8 pa = *(const bf16x8*)(&Ps[wave][(lane & 15) * 40 + (lane >> 4) * 8]);
            #pragma unroll
            for (int nt = 0; nt < 8; nt++) {
                bf16x8 vf = *(const bf16x8*)(&VsT[(nt * 16 + (lane & 15)) * 40 + (lane >> 4) * 8]);
                o[nt] = __builtin_amdgcn_mfma_f32_16x16x32_bf16(pa, vf, o[nt], 0, 0, 0);
            }
        }
    }

    #pragma unroll
    for (int j = 0; j < 4; j++) {
        float inv = 1.0f / l_run[j];
        size_t row = baseTok + q0 + (lane >> 4) * 4 + j;
        #pragma unroll
        for (int nt = 0; nt < 8; nt++)
            Ao[row * 512 + h * 128 + nt * 16 + (lane & 15)] = f2bf(o[nt][j] * inv);
    }
}

// ---------------------------------------------------------------------------
extern "C" void kernel_launch(void* const* d_in, const int* in_sizes, int n_in,
                              void* d_out, int out_size, void* d_ws, size_t ws_size,
                              hipStream_t stream) {
    const float* x     = (const float*)d_in[0];
    const float* Wq    = (const float*)d_in[1];
    const float* Wk    = (const float*)d_in[2];
    const float* bk    = (const float*)d_in[3];
    const float* Wv    = (const float*)d_in[4];
    const float* Wproj = (const float*)d_in[5];
    const float* bproj = (const float*)d_in[6];
    const float* w1    = (const float*)d_in[7];
    const float* w2    = (const float*)d_in[8];
    const float* Wi    = (const float*)d_in[9];
    const float* Wo    = (const float*)d_in[10];
    float* out = (float*)d_out;
    (void)in_sizes; (void)n_in; (void)out_size;

    char* ws = (char*)d_ws;
    size_t off = 0;
    auto alloc = [&](size_t bytes) -> void* {
        void* p = ws + off;
        off += (bytes + 255) & ~(size_t)255;
        return p;
    };
    // ---- persistent weights (prepped once per call) ----
    ushort_t* WqkvT    = (ushort_t*)alloc((size_t)1536 * 512 * 2);
    float*    bias1536 = (float*)   alloc((size_t)1536 * 4);
    ushort_t* WprojT   = (ushort_t*)alloc((size_t)512 * 512 * 2);
    ushort_t* WiT      = (ushort_t*)alloc((size_t)4096 * 512 * 2);
    ushort_t* WoT2     = (ushort_t*)alloc((size_t)512 * 4096 * 2);
    const size_t weightBytes = off;

    // ---- choose batch-chunk count so scratch fits ws_size ----
    // per-chunk scratch: hb Mc*512*2, big Mc*4096*2, zb Mc*512*2, s Mc*4
    int nchunks = 1;
    while (nchunks < 64) {
        size_t Mc = (size_t)TOKENS / nchunks;
        size_t need = weightBytes + Mc * 512 * 2 + Mc * 4096 * 2
                    + Mc * 512 * 2 + Mc * 4 + 8192;
        if (need <= ws_size) break;
        nchunks *= 2;
    }
    const size_t Mc = (size_t)TOKENS / nchunks;          // tokens per chunk
    const int    nbChunk = B_BATCH / nchunks;            // batches per chunk

    ushort_t* hb   = (ushort_t*)alloc(Mc * 512 * 2);     // h -> attn out (time-shared)
    ushort_t* big  = (ushort_t*)alloc(Mc * 4096 * 2);    // qkv (1536 wide) -> hmid (4096 wide)
    ushort_t* zb   = (ushort_t*)alloc(Mc * 512 * 2);     // z (bf16)
    float*    srow = (float*)   alloc(Mc * 4);           // per-row x2 scale

    // ---- weight prep ----
    prep_qkv <<<(1536 * 512 + 255) / 256, 256, 0, stream>>>(Wq, Wk, Wv, WqkvT);
    prep_bias<<<6, 256, 0, stream>>>(bk, bias1536);
    prep_proj<<<1024, 256, 0, stream>>>(Wproj, WprojT);
    prep_wi  <<<8192, 256, 0, stream>>>(Wi, WiT);
    prep_wo  <<<8192, 256, 0, stream>>>(Wo, WoT2);

    for (int ck = 0; ck < nchunks; ck++) {
        const size_t t0 = (size_t)ck * Mc;
        const float* xC   = x + t0 * 512;
        float*       oC   = out + t0 * 512;
        const int    Mi   = (int)Mc;
        const int    mt   = Mi / 256;                    // 256-row M-tiles

        // h = rmsnorm(x, w1) -> hb (bf16)
        rmsnorm_kernel<<<Mi / 4, 256, 0, stream>>>(xC, w1, hb);
        // QKV = h @ WqkvT^T + bias -> big (bf16, width 1536)
        gemm256<0><<<mt * 6, 512, 0, stream>>>(
            hb, WqkvT, nullptr, big, bias1536, nullptr, nullptr, nullptr, 1536, 512);
        // attention -> hb (bf16, width 512)
        attn_kernel<<<dim3(T_SEQ / 64, nbChunk * H_HEADS), 256, 0, stream>>>(big, hb);
        // z = x + attn @ Wproj + bproj -> zb (bf16; halves proj write traffic)
        gemm256<1><<<mt * 2, 512, 0, stream>>>(
            hb, WprojT, nullptr, zb, bproj, xC, nullptr, nullptr, 512, 512);
        // x2 row scale: s[m] = w2 * rsqrt(mean(zb[m]^2) + eps)
        rowscale_kernel<<<Mi / 4, 256, 0, stream>>>(zb, w2, srow);
        // hmid = gelu(s_m * (zb @ WiT^T)) -> big
        gemm256<2><<<mt * 16, 512, 0, stream>>>(
            zb, WiT, nullptr, big, nullptr, nullptr, nullptr, srow, 4096, 512);
        // out = s_m*zb + hmid @ WoT2^T   (0.5 folded into WoT2, K=4096)
        gemm256<3><<<mt * 2, 512, 0, stream>>>(
            big, WoT2, oC, nullptr, nullptr, nullptr, zb, srow, 512, 4096);
    }
}

// Round 16
// 2270.612 us; speedup vs baseline: 1.1414x; 1.0338x over previous
//
#include <hip/hip_runtime.h>
#include <cstdint>
#include <cstddef>

#define TOKENS 131072      // B*T = 512*256
#define B_BATCH 512
#define T_SEQ 256
#define C_DIM 512
#define H_HEADS 4
#define HS_DIM 128
#define FF_DIM 2048
#define EPS_RMS 1e-8f
#define SM_SCALE 0.044194173824159216f   // 512^-0.5

typedef short bf16x8 __attribute__((ext_vector_type(8)));
typedef float f32x4 __attribute__((ext_vector_type(4)));
typedef unsigned short ushort_t;

__device__ __forceinline__ ushort_t f2bf(float f) {
    uint32_t u = __builtin_bit_cast(uint32_t, f);
    u += 0x7FFFu + ((u >> 16) & 1u);   // round-to-nearest-even
    return (ushort_t)(u >> 16);
}

__device__ __forceinline__ float bf2f(ushort_t u) {
    return __builtin_bit_cast(float, (uint32_t)u << 16);
}

// tanh-form GELU: validated r7/r10/r11/r13/r15 (absmax unchanged at 0.03125).
__device__ __forceinline__ float gelu_f(float x) {
    float u = 0.7978845608028654f * x + 0.035677408136300125f * (x * x * x);
    float e = __expf(2.0f * u);                 // inf-safe: e=inf -> t=1
    float t = 1.0f - 2.0f / (1.0f + e);         // tanh(u)
    return 0.5f * x * (1.0f + t);
}

// async global->LDS, 16B/lane. Dest must be wave-uniform; HW adds lane*16.
__device__ __forceinline__ void stage8k(ushort_t* lds, const ushort_t* g) {
    __builtin_amdgcn_global_load_lds(
        (const __attribute__((address_space(1))) uint32_t*)g,
        (__attribute__((address_space(3))) uint32_t*)lds,
        16, 0, 0);
}

// ---------------------------------------------------------------------------
// Weight prep: fp32 -> bf16, transposed to N x K row-major
// ---------------------------------------------------------------------------
__global__ void prep_qkv(const float* __restrict__ Wq, const float* __restrict__ Wk,
                         const float* __restrict__ Wv, ushort_t* __restrict__ WqkvT) {
    int idx = blockIdx.x * 256 + threadIdx.x;       // over 1536*512
    if (idx >= 1536 * 512) return;
    int n = idx >> 9;
    int k = idx & 511;
    int h = (n & 511) >> 7;
    int d = n & 127;
    float v;
    size_t s = ((size_t)h * 512 + k) * 128 + d;     // (H,C,HS)
    if (n < 512)       v = Wq[s];
    else if (n < 1024) v = Wk[s];
    else               v = Wv[s];
    WqkvT[idx] = f2bf(v);
}

__global__ void prep_bias(const float* __restrict__ bk, float* __restrict__ bias1536) {
    int n = blockIdx.x * 256 + threadIdx.x;
    if (n >= 1536) return;
    bias1536[n] = (n >= 512 && n < 1024) ? bk[n - 512] : 0.0f;   // bk flat (H,HS)
}

__global__ void prep_proj(const float* __restrict__ Wproj, ushort_t* __restrict__ WprojT) {
    int idx = blockIdx.x * 256 + threadIdx.x;       // over 512*512
    if (idx >= 512 * 512) return;
    int n = idx >> 9, k = idx & 511;
    WprojT[idx] = f2bf(Wproj[(size_t)k * 512 + n]);
}

__global__ void prep_wi(const float* __restrict__ Wi, ushort_t* __restrict__ WiT) {
    int idx = blockIdx.x * 256 + threadIdx.x;       // over 2*2048*512
    if (idx >= 2 * 2048 * 512) return;
    int b = idx >> 20;
    int rem = idx & 1048575;
    int f = rem >> 9, c = rem & 511;                // WiT[b*2048+f][c] = [4096][512]
    WiT[idx] = f2bf(Wi[((size_t)b * 512 + c) * 2048 + f]);
}

// WoT2[c][br*2048+f] = 0.5 * Wo[br][f][c]  -> [512][4096] row-major over K=4096
__global__ void prep_wo(const float* __restrict__ Wo, ushort_t* __restrict__ WoT2) {
    int idx = blockIdx.x * 256 + threadIdx.x;       // over 512*4096
    if (idx >= 512 * 4096) return;
    int c  = idx >> 12;
    int n2 = idx & 4095;
    int br = n2 >> 11;
    int f  = n2 & 2047;
    WoT2[idx] = f2bf(0.5f * Wo[(((size_t)br * 2048 + f) * 512) + c]);
}

// ---------------------------------------------------------------------------
// RMSNorm (first norm only): one wave per token, f32 in -> bf16 out.
// ---------------------------------------------------------------------------
__global__ __launch_bounds__(256) void rmsnorm_kernel(const float* __restrict__ in,
                                                      const float* __restrict__ wptr,
                                                      ushort_t* __restrict__ outb) {
    const int lane = threadIdx.x & 63;
    const int wave = threadIdx.x >> 6;
    const size_t token = (size_t)blockIdx.x * 4 + wave;
    const float* row = in + token * 512;
    float4 v0 = *(const float4*)(row + lane * 8);
    float4 v1 = *(const float4*)(row + lane * 8 + 4);
    float ss = v0.x*v0.x + v0.y*v0.y + v0.z*v0.z + v0.w*v0.w
             + v1.x*v1.x + v1.y*v1.y + v1.z*v1.z + v1.w*v1.w;
    #pragma unroll
    for (int d = 32; d; d >>= 1) ss += __shfl_xor(ss, d);
    float scale = wptr[0] * rsqrtf(ss * (1.0f / 512.0f) + EPS_RMS);
    float vals[8] = {v0.x, v0.y, v0.z, v0.w, v1.x, v1.y, v1.z, v1.w};
    union { ushort_t us[8]; uint4 u4; } pk;
    #pragma unroll
    for (int i = 0; i < 8; i++) pk.us[i] = f2bf(vals[i] * scale);
    *(uint4*)(outb + token * 512 + lane * 8) = pk.u4;
}

// ---------------------------------------------------------------------------
// Row-scale kernel: s[m] = w2 * rsqrt(mean(zb[m]^2) + eps); applied in the
// FFN GEMM epilogues via linearity ((s*z)@W = s*(z@W)).  (r15, validated)
// ---------------------------------------------------------------------------
__global__ __launch_bounds__(256) void rowscale_kernel(const ushort_t* __restrict__ zb,
                                                       const float* __restrict__ wptr,
                                                       float* __restrict__ s) {
    const int lane = threadIdx.x & 63;
    const int wave = threadIdx.x >> 6;
    const size_t token = (size_t)blockIdx.x * 4 + wave;
    bf16x8 v = *(const bf16x8*)(zb + token * 512 + lane * 8);
    float ss = 0.0f;
    #pragma unroll
    for (int i = 0; i < 8; i++) { float f = bf2f((ushort_t)v[i]); ss += f * f; }
    #pragma unroll
    for (int d = 32; d; d >>= 1) ss += __shfl_xor(ss, d);
    if (lane == 0) s[token] = wptr[0] * rsqrtf(ss * (1.0f / 512.0f) + EPS_RMS);
}

// ---------------------------------------------------------------------------
// GEMM 256x256, BK=64, 8-phase FIFO counted-vmcnt(6), 128KB LDS — the r13/r15
// kernel (best measured, 0 conflicts). Schedule/ledger unchanged (see r13).
// MODE 0: Cb = bf16(acc + bias[c])              (QK projection)
// MODE 1: Cb = bf16(acc + bias[c] + X[idx])     (proj + residual -> z bf16)
// MODE 2: Cb = bf16(gelu(sc[r] * acc))          (FFN up; rms-scale folded)
// MODE 3: Cf = sc[r] * bf2f(Xb[idx]) + acc      (FFN down; x2 = s*z residual)
// MODE 4: Cb = bf16(acc)                        (V^T GEMM, no bias)
// ---------------------------------------------------------------------------
template<int MODE>
__global__ __launch_bounds__(512) void gemm256(
    const ushort_t* __restrict__ A, const ushort_t* __restrict__ Bt,
    float* Cf, ushort_t* __restrict__ Cb,
    const float* __restrict__ bias, const float* __restrict__ X,
    const ushort_t* __restrict__ Xb, const float* __restrict__ sc,
    int N, int K)
{
    __shared__ __align__(16) ushort_t S[2][2][256 * 64];   // [buf][0=A,1=B] 128KB
    const int tid  = threadIdx.x;
    const int lane = tid & 63;
    const int wave = tid >> 6;
    const int wm = wave >> 2;          // 0..1
    const int wn = wave & 3;           // 0..3

    // XCD-chunked bijective swizzle (nwg % 8 == 0 for all our grids)
    const int nwg  = (int)gridDim.x;
    const int orig = (int)blockIdx.x;
    const int wgid = (orig & 7) * (nwg >> 3) + (orig >> 3);
    const int gx   = N >> 8;
    const int bm = (wgid / gx) << 8;
    const int bn = (wgid % gx) << 8;

    const int NT = K >> 6;             // K-tiles of 64 (NT >= 8, even, here)

    // pre-swizzled global source column (elements): granule (lane&7)^(lane>>3)
    const int sx = (((lane & 7) ^ (lane >> 3)) << 3);

    auto stA = [&](int dbuf, int part, int ts) {
        int tc = ts < NT ? ts : NT - 1;
        #pragma unroll
        for (int i = 0; i < 2; i++) {
            int rbase = i * 128 + part * 64 + wave * 8;
            stage8k(&S[dbuf][0][rbase * 64],
                    A + (size_t)(bm + rbase + (lane >> 3)) * K + tc * 64 + sx);
        }
    };
    auto stB = [&](int dbuf, int part, int ts) {
        int tc = ts < NT ? ts : NT - 1;
        #pragma unroll
        for (int i = 0; i < 2; i++) {
            int rbase = i * 128 + (wave >> 2) * 64 + part * 32 + (wave & 3) * 8;
            stage8k(&S[dbuf][1][rbase * 64],
                    Bt + (size_t)(bn + rbase + (lane >> 3)) * K + tc * 64 + sx);
        }
    };

    const int r16 = lane & 15;
    const int l7  = lane & 7;
    const int q   = lane >> 4;
    const int ge0 = ((q)     ^ l7) << 3;   // k-slice 0 granule elems
    const int ge1 = ((4 + q) ^ l7) << 3;   // k-slice 1

    f32x4 acc[8][4] = {};
    bf16x8 a[4][2], bA[2][2], bB[2][2];

#define LDA(BUF, MH) { _Pragma("unroll") for (int mf = 0; mf < 4; mf++) { \
    int R = wm * 128 + (MH) * 64 + mf * 16 + r16; \
    a[mf][0] = *(const bf16x8*)&S[BUF][0][R * 64 + ge0]; \
    a[mf][1] = *(const bf16x8*)&S[BUF][0][R * 64 + ge1]; } }
#define LDB(BUF, NH, breg) { _Pragma("unroll") for (int nf = 0; nf < 2; nf++) { \
    int R = wn * 64 + (NH) * 32 + nf * 16 + r16; \
    breg[nf][0] = *(const bf16x8*)&S[BUF][1][R * 64 + ge0]; \
    breg[nf][1] = *(const bf16x8*)&S[BUF][1][R * 64 + ge1]; } }
#define MM(MH, NH, breg) { __builtin_amdgcn_s_setprio(1); \
    _Pragma("unroll") for (int mf = 0; mf < 4; mf++) \
    _Pragma("unroll") for (int nf = 0; nf < 2; nf++) { \
        f32x4 t0 = __builtin_amdgcn_mfma_f32_16x16x32_bf16(a[mf][0], breg[nf][0], acc[(MH)*4+mf][(NH)*2+nf], 0, 0, 0); \
        acc[(MH)*4+mf][(NH)*2+nf] = __builtin_amdgcn_mfma_f32_16x16x32_bf16(a[mf][1], breg[nf][1], t0, 0, 0, 0); } \
    __builtin_amdgcn_s_setprio(0); }
#define BAR    __builtin_amdgcn_s_barrier()
#define WAITL  { asm volatile("s_waitcnt lgkmcnt(0)" ::: "memory"); __builtin_amdgcn_sched_barrier(0); }
#define WAITLV { asm volatile("s_waitcnt lgkmcnt(0)\n\ts_waitcnt vmcnt(6)" ::: "memory"); __builtin_amdgcn_sched_barrier(0); }

    // prologue: FIFO half-tiles [A0,B0,B1,A1](0) -> buf0, [A0,B0,B1](1) -> buf1
    stA(0, 0, 0); stB(0, 0, 0); stB(0, 1, 0); stA(0, 1, 0);
    stA(1, 0, 1); stB(1, 0, 1); stB(1, 1, 1);
    asm volatile("s_waitcnt vmcnt(6)" ::: "memory");
    __builtin_amdgcn_sched_barrier(0);
    BAR;

    const int NI = NT >> 1;
    for (int I = 0; I < NI; ++I) {
        const int t = 2 * I;
        // ---- K-tile t (buf0); single end-of-phase barriers ----
        LDA(0, 0); LDB(0, 0, bA);  stA(1, 1, t + 1);  WAITL;  MM(0, 0, bA); BAR;  // P1
        LDB(0, 1, bB);             stA(0, 0, t + 2);  WAITL;  MM(0, 1, bB); BAR;  // P2
        LDA(0, 1);                 stB(0, 0, t + 2);  WAITL;  MM(1, 1, bB); BAR;  // P3
                                   stB(0, 1, t + 2);  WAITLV; MM(1, 0, bA); BAR;  // P4
        // ---- K-tile t+1 (buf1) ----
        LDA(1, 0); LDB(1, 0, bA);  stA(0, 1, t + 2);  WAITL;  MM(0, 0, bA); BAR;  // P5
        LDB(1, 1, bB);             stA(1, 0, t + 3);  WAITL;  MM(0, 1, bB); BAR;  // P6
        LDA(1, 1);                 stB(1, 0, t + 3);  WAITL;  MM(1, 1, bB); BAR;  // P7
                                   stB(1, 1, t + 3);  WAITLV; MM(1, 0, bA); BAR;  // P8
    }
#undef LDA
#undef LDB
#undef MM
#undef BAR
#undef WAITL
#undef WAITLV

    #pragma unroll
    for (int mf = 0; mf < 8; mf++) {
        #pragma unroll
        for (int nf = 0; nf < 4; nf++) {
            #pragma unroll
            for (int j = 0; j < 4; j++) {
                int r = bm + wm * 128 + mf * 16 + (lane >> 4) * 4 + j;
                int c = bn + wn * 64 + nf * 16 + r16;
                float v = acc[mf][nf][j];
                size_t idx = (size_t)r * N + c;
                if (MODE == 0)      { Cb[idx] = f2bf(v + bias[c]); }
                else if (MODE == 1) { Cb[idx] = f2bf(v + bias[c] + X[idx]); }
                else if (MODE == 2) { Cb[idx] = f2bf(gelu_f(sc[r] * v)); }
                else if (MODE == 3) { Cf[idx] = sc[r] * bf2f(Xb[idx]) + v; }
                else                { Cb[idx] = f2bf(v); }
            }
        }
    }
}

// ---------------------------------------------------------------------------
// Fused causal attention v2. KVBLK=64, V consumed from the PRE-TRANSPOSED
// Vt[dh][token] buffer (produced directly by the V-GEMM with swapped
// operands) — the 16-way-conflicted in-kernel V transpose is gone, and
// barriers halve (2 per 64 keys vs 4). QK buffer is [token][1024]
// (q at h*128, k at 512+h*128). All LDS strides chosen so row-stride mod
// 128B = 8B -> vector reads are 2-way (free, m136).
// Block = 4 waves; wave owns 16 q rows; block covers 64 q rows of one (b,h).
// ---------------------------------------------------------------------------
__global__ __launch_bounds__(256) void attn_kernel(const ushort_t* __restrict__ QK,
                                                   const ushort_t* __restrict__ Vt,
                                                   ushort_t* __restrict__ Ao,
                                                   int McTok) {
    __shared__ __align__(16) ushort_t Ks[64 * 136];    // [key][d], pad 136
    __shared__ __align__(16) ushort_t Vs[128 * 72];    // [d][key], pad 72
    __shared__ __align__(16) ushort_t Ps[4][16 * 72];  // per-wave P, pad 72
    const int tid  = threadIdx.x;
    const int lane = tid & 63;
    const int wave = tid >> 6;
    const int qtile = blockIdx.x;                 // 0..3
    const int bh = blockIdx.y;                    // local_b * 4 + h
    const int b = bh >> 2;
    const int h = bh & 3;
    const int q0 = qtile * 64 + wave * 16;
    const size_t baseTok = (size_t)b * T_SEQ;
    const int r16 = lane & 15;
    const int q4  = lane >> 4;

    bf16x8 qf[4];
    {
        const ushort_t* qrow = QK + (baseTok + q0 + r16) * 1024 + h * 128 + q4 * 8;
        #pragma unroll
        for (int dc = 0; dc < 4; dc++)
            qf[dc] = *(const bf16x8*)(qrow + dc * 32);
    }

    float m_run[4], l_run[4];
    f32x4 o[8];
    #pragma unroll
    for (int j = 0; j < 4; j++) { m_run[j] = -INFINITY; l_run[j] = 0.0f; }
    #pragma unroll
    for (int nt = 0; nt < 8; nt++) o[nt] = f32x4{0.f, 0.f, 0.f, 0.f};

    for (int kc = 0; kc <= qtile; kc++) {
        const int kbase = kc * 64;
        __syncthreads();
        // stage K: 64 keys x 128 d; 4 x uint4 per thread, coalesced
        #pragma unroll
        for (int i = 0; i < 4; i++) {
            int g = i * 256 + tid;          // 64 rows x 16 granules
            int row = g >> 4, c16 = g & 15;
            uint4 vk = *(const uint4*)(QK + (baseTok + kbase + row) * 1024
                                       + 512 + h * 128 + c16 * 8);
            *(uint4*)(&Ks[row * 136 + c16 * 8]) = vk;
        }
        // stage V^T: 128 d x 64 keys; 4 x uint4 per thread
        #pragma unroll
        for (int i = 0; i < 4; i++) {
            int g = i * 256 + tid;          // 128 rows x 8 granules
            int d = g >> 3, c8 = g & 7;
            uint4 vv = *(const uint4*)(Vt + (size_t)(h * 128 + d) * McTok
                                       + baseTok + kbase + c8 * 8);
            *(uint4*)(&Vs[d * 72 + c8 * 8]) = vv;
        }
        __syncthreads();

        // QK^T: 4 key-tiles of 16
        f32x4 s[4];
        #pragma unroll
        for (int kt = 0; kt < 4; kt++) s[kt] = f32x4{0.f, 0.f, 0.f, 0.f};
        #pragma unroll
        for (int kt = 0; kt < 4; kt++)
            #pragma unroll
            for (int dc = 0; dc < 4; dc++) {
                bf16x8 kf = *(const bf16x8*)(&Ks[(kt * 16 + r16) * 136 + dc * 32 + q4 * 8]);
                s[kt] = __builtin_amdgcn_mfma_f32_16x16x32_bf16(qf[dc], kf, s[kt], 0, 0, 0);
            }

        // online softmax (rows j; key = kbase + kt*16 + r16)
        float alpha[4];
        #pragma unroll
        for (int j = 0; j < 4; j++) {
            int qrow = q0 + q4 * 4 + j;
            float sv[4];
            #pragma unroll
            for (int kt = 0; kt < 4; kt++) {
                int key = kbase + kt * 16 + r16;
                sv[kt] = (key <= qrow) ? s[kt][j] * SM_SCALE : -INFINITY;
            }
            float mx = fmaxf(fmaxf(sv[0], sv[1]), fmaxf(sv[2], sv[3]));
            #pragma unroll
            for (int d = 1; d < 16; d <<= 1) mx = fmaxf(mx, __shfl_xor(mx, d));
            float mnew = fmaxf(m_run[j], mx);
            float aa = expf(m_run[j] - mnew);
            float rs = 0.0f;
            int rloc = q4 * 4 + j;
            #pragma unroll
            for (int kt = 0; kt < 4; kt++) {
                float p = expf(sv[kt] - mnew);
                rs += p;
                Ps[wave][rloc * 72 + kt * 16 + r16] = f2bf(p);
            }
            #pragma unroll
            for (int d = 1; d < 16; d <<= 1) rs += __shfl_xor(rs, d);
            l_run[j] = l_run[j] * aa + rs;
            m_run[j] = mnew;
            alpha[j] = aa;
        }
        #pragma unroll
        for (int nt = 0; nt < 8; nt++)
            #pragma unroll
            for (int j = 0; j < 4; j++) o[nt][j] *= alpha[j];

        // PV: A = P fragment [q][key], B = Vs[d][key]; 2 k-groups of 32
        #pragma unroll
        for (int kg = 0; kg < 2; kg++) {
            bf16x8 pa = *(const bf16x8*)(&Ps[wave][r16 * 72 + kg * 32 + q4 * 8]);
            #pragma unroll
            for (int nt = 0; nt < 8; nt++) {
                bf16x8 vf = *(const bf16x8*)(&Vs[(nt * 16 + r16) * 72 + kg * 32 + q4 * 8]);
                o[nt] = __builtin_amdgcn_mfma_f32_16x16x32_bf16(pa, vf, o[nt], 0, 0, 0);
            }
        }
    }

    #pragma unroll
    for (int j = 0; j < 4; j++) {
        float inv = 1.0f / l_run[j];
        size_t row = baseTok + q0 + q4 * 4 + j;
        #pragma unroll
        for (int nt = 0; nt < 8; nt++)
            Ao[row * 512 + h * 128 + nt * 16 + r16] = f2bf(o[nt][j] * inv);
    }
}

// ---------------------------------------------------------------------------
extern "C" void kernel_launch(void* const* d_in, const int* in_sizes, int n_in,
                              void* d_out, int out_size, void* d_ws, size_t ws_size,
                              hipStream_t stream) {
    const float* x     = (const float*)d_in[0];
    const float* Wq    = (const float*)d_in[1];
    const float* Wk    = (const float*)d_in[2];
    const float* bk    = (const float*)d_in[3];
    const float* Wv    = (const float*)d_in[4];
    const float* Wproj = (const float*)d_in[5];
    const float* bproj = (const float*)d_in[6];
    const float* w1    = (const float*)d_in[7];
    const float* w2    = (const float*)d_in[8];
    const float* Wi    = (const float*)d_in[9];
    const float* Wo    = (const float*)d_in[10];
    float* out = (float*)d_out;
    (void)in_sizes; (void)n_in; (void)out_size;

    char* ws = (char*)d_ws;
    size_t off = 0;
    auto alloc = [&](size_t bytes) -> void* {
        void* p = ws + off;
        off += (bytes + 255) & ~(size_t)255;
        return p;
    };
    // ---- persistent weights ----
    ushort_t* WqkvT    = (ushort_t*)alloc((size_t)1536 * 512 * 2);
    float*    bias1536 = (float*)   alloc((size_t)1536 * 4);
    ushort_t* WprojT   = (ushort_t*)alloc((size_t)512 * 512 * 2);
    ushort_t* WiT      = (ushort_t*)alloc((size_t)4096 * 512 * 2);
    ushort_t* WoT2     = (ushort_t*)alloc((size_t)512 * 4096 * 2);
    const size_t weightBytes = off;

    // ---- chunking: hb Mc*1024B, big Mc*8192B, zb Mc*1024B, vt Mc*1024B, s 4B
    int nchunks = 1;
    while (nchunks < 64) {
        size_t Mc = (size_t)TOKENS / nchunks;
        size_t need = weightBytes + Mc * 512 * 2 + Mc * 4096 * 2
                    + Mc * 512 * 2 + Mc * 512 * 2 + Mc * 4 + 8192;
        if (need <= ws_size) break;
        nchunks *= 2;
    }
    const size_t Mc = (size_t)TOKENS / nchunks;
    const int    nbChunk = B_BATCH / nchunks;

    ushort_t* hb   = (ushort_t*)alloc(Mc * 512 * 2);    // h -> attn out
    ushort_t* big  = (ushort_t*)alloc(Mc * 4096 * 2);   // qk (1024) -> hmid (4096)
    ushort_t* zb   = (ushort_t*)alloc(Mc * 512 * 2);    // z (bf16)
    ushort_t* vt   = (ushort_t*)alloc(Mc * 512 * 2);    // V^T [dh][token]
    float*    srow = (float*)   alloc(Mc * 4);          // per-row x2 scale

    // ---- weight prep ----
    prep_qkv <<<(1536 * 512 + 255) / 256, 256, 0, stream>>>(Wq, Wk, Wv, WqkvT);
    prep_bias<<<6, 256, 0, stream>>>(bk, bias1536);
    prep_proj<<<1024, 256, 0, stream>>>(Wproj, WprojT);
    prep_wi  <<<8192, 256, 0, stream>>>(Wi, WiT);
    prep_wo  <<<8192, 256, 0, stream>>>(Wo, WoT2);

    for (int ck = 0; ck < nchunks; ck++) {
        const size_t t0 = (size_t)ck * Mc;
        const float* xC   = x + t0 * 512;
        float*       oC   = out + t0 * 512;
        const int    Mi   = (int)Mc;
        const int    mt   = Mi / 256;                    // 256-row M-tiles

        // h = rmsnorm(x, w1) -> hb (bf16)
        rmsnorm_kernel<<<Mi / 4, 256, 0, stream>>>(xC, w1, hb);
        // QK = h @ Wqk^T + bias -> big (bf16, width 1024)
        gemm256<0><<<mt * 4, 512, 0, stream>>>(
            hb, WqkvT, nullptr, big, bias1536, nullptr, nullptr, nullptr, 1024, 512);
        // V^T = Wv^T @ h^T  (swapped operands: A=WvT[512][512], Bt=hb[Mc][512])
        //   -> vt[dh][token], coalesced epilogue; attention consumes directly.
        gemm256<4><<<2 * (Mi / 256), 512, 0, stream>>>(
            WqkvT + (size_t)1024 * 512, hb, nullptr, vt,
            nullptr, nullptr, nullptr, nullptr, Mi, 512);
        // attention -> hb (bf16, width 512)
        attn_kernel<<<dim3(T_SEQ / 64, nbChunk * H_HEADS), 256, 0, stream>>>(big, vt, hb, Mi);
        // z = x + attn @ Wproj + bproj -> zb (bf16)
        gemm256<1><<<mt * 2, 512, 0, stream>>>(
            hb, WprojT, nullptr, zb, bproj, xC, nullptr, nullptr, 512, 512);
        // x2 row scale
        rowscale_kernel<<<Mi / 4, 256, 0, stream>>>(zb, w2, srow);
        // hmid = gelu(s_m * (zb @ WiT^T)) -> big
        gemm256<2><<<mt * 16, 512, 0, stream>>>(
            zb, WiT, nullptr, big, nullptr, nullptr, nullptr, srow, 4096, 512);
        // out = s_m*zb + hmid @ WoT2^T
        gemm256<3><<<mt * 2, 512, 0, stream>>>(
            big, WoT2, oC, nullptr, nullptr, nullptr, zb, srow, 512, 4096);
    }
}